// Round 1
// baseline (430.247 us; speedup 1.0000x reference)
//
#include <hip/hip_runtime.h>

// GCN graph embedding: N=50000, E=600000, F=128 throughout, G=64 graphs.
// Pipeline:
//   deg count -> dinv -> exclusive scan -> CSR fill
//   bufA = x @ W1            (GEMM, fp32 vector)
//   bufB = relu(gather(bufA) + b1)
//   bufA = bufB @ W2
//   bufB = relu(gather(bufA) + b2)
//   sums/counts = pool(bufB, batch)   (sorted batch, binary-search bounds)
//   out = (sums/counts) @ Wl + bl

#define FD 128

__global__ void count_deg(const int* __restrict__ dst, int* __restrict__ cnt, int E) {
    int e = blockIdx.x * 256 + threadIdx.x;
    if (e < E) atomicAdd(&cnt[dst[e]], 1);
}

__global__ void compute_dinv(const int* __restrict__ cnt, float* __restrict__ dinv, int n) {
    int i = blockIdx.x * 256 + threadIdx.x;
    if (i < n) dinv[i] = rsqrtf((float)cnt[i] + 1.0f);  // +1 self loop
}

__global__ __launch_bounds__(1024) void scan1(const int* __restrict__ cnt, int* __restrict__ offs,
                                              int* __restrict__ partials, int n) {
    __shared__ int s[1024];
    int tid = threadIdx.x;
    int i = blockIdx.x * 1024 + tid;
    int v = (i < n) ? cnt[i] : 0;
    s[tid] = v;
    __syncthreads();
    for (int off = 1; off < 1024; off <<= 1) {
        int t = (tid >= off) ? s[tid - off] : 0;
        __syncthreads();
        s[tid] += t;
        __syncthreads();
    }
    if (i < n) offs[i] = s[tid] - v;            // exclusive within block
    if (tid == 1023) partials[blockIdx.x] = s[1023];
}

__global__ void scan2(int* partials, int nb) {
    if (threadIdx.x == 0 && blockIdx.x == 0) {
        int run = 0;
        for (int b = 0; b < nb; b++) { int t = partials[b]; partials[b] = run; run += t; }
    }
}

__global__ __launch_bounds__(1024) void scan3(int* __restrict__ offs, const int* __restrict__ partials, int n) {
    int i = blockIdx.x * 1024 + threadIdx.x;
    if (i < n) offs[i] += partials[blockIdx.x];
}

__global__ void fill_csr(const int* __restrict__ src, const int* __restrict__ dst,
                         const int* __restrict__ offs, int* __restrict__ cursor,
                         int* __restrict__ csr, int E) {
    int e = blockIdx.x * 256 + threadIdx.x;
    if (e < E) {
        int d = dst[e];
        int p = atomicAdd(&cursor[d], 1);
        csr[offs[d] + p] = src[e];
    }
}

// Y[rows x 128] = X[rows x 128] @ W[128 x 128]; 32 rows per 256-thread block.
__global__ __launch_bounds__(256) void gemm128(const float* __restrict__ X, const float* __restrict__ W,
                                               float* __restrict__ Y, int rows) {
    __shared__ __align__(16) float xs[32][FD];
    int tid = threadIdx.x;
    int r0 = blockIdx.x * 32;

    const float4* Xv = (const float4*)(X + (size_t)r0 * FD);
    float4* xsv = (float4*)&xs[0][0];
    #pragma unroll
    for (int j = 0; j < 4; j++) {
        int idx = tid + j * 256;                    // float4 index within tile (0..1023)
        size_t gi = (size_t)r0 * 32 + idx;          // global float4 index
        float4 v = make_float4(0.f, 0.f, 0.f, 0.f);
        if (gi < (size_t)rows * 32) v = Xv[idx];
        xsv[idx] = v;
    }
    __syncthreads();

    int c4 = (tid & 31) * 4;   // 4 output cols
    int rg = tid >> 5;         // 8 row groups x 4 rows
    float acc[4][4] = {};

    #pragma unroll 8
    for (int k0 = 0; k0 < FD; k0 += 4) {
        float w[4][4];
        #pragma unroll
        for (int j = 0; j < 4; j++) {
            float4 wv = *(const float4*)&W[(size_t)(k0 + j) * FD + c4];
            w[j][0] = wv.x; w[j][1] = wv.y; w[j][2] = wv.z; w[j][3] = wv.w;
        }
        #pragma unroll
        for (int r = 0; r < 4; r++) {
            float4 xv = *(const float4*)&xs[rg * 4 + r][k0];
            #pragma unroll
            for (int c = 0; c < 4; c++) {
                acc[r][c] += xv.x * w[0][c];
                acc[r][c] += xv.y * w[1][c];
                acc[r][c] += xv.z * w[2][c];
                acc[r][c] += xv.w * w[3][c];
            }
        }
    }

    #pragma unroll
    for (int r = 0; r < 4; r++) {
        int row = r0 + rg * 4 + r;
        if (row < rows) {
            float4 o = make_float4(acc[r][0], acc[r][1], acc[r][2], acc[r][3]);
            *(float4*)&Y[(size_t)row * FD + c4] = o;
        }
    }
}

// out[n][f] = relu( dinv[n] * (sum_{s in in(n)} xw[s][f]*dinv[s] + xw[n][f]*dinv[n]) + bias[f] )
__global__ __launch_bounds__(256) void gcn_gather(const float* __restrict__ xw, const float* __restrict__ dinv,
                                                  const int* __restrict__ offs, const int* __restrict__ cnt,
                                                  const int* __restrict__ csr, const float* __restrict__ bias,
                                                  float* __restrict__ out, int n) {
    int node = blockIdx.x * 2 + (threadIdx.x >> 7);
    int f = threadIdx.x & 127;
    if (node >= n) return;
    float dn = dinv[node];
    float acc = xw[(size_t)node * FD + f] * dn;     // self loop (gets *dn again below)
    int s0 = offs[node];
    int e0 = s0 + cnt[node];
    for (int i = s0; i < e0; i++) {
        int s = csr[i];
        acc += xw[(size_t)s * FD + f] * dinv[s];
    }
    float v = fmaf(acc, dn, bias[f]);
    out[(size_t)node * FD + f] = fmaxf(v, 0.0f);
}

__global__ __launch_bounds__(128) void pool_partial(const float* __restrict__ h, const int* __restrict__ batch,
                                                    float* __restrict__ sums, int* __restrict__ counts, int n) {
    int g = blockIdx.x >> 3;
    int c = blockIdx.x & 7;
    int f = threadIdx.x;
    // lower_bound(g), lower_bound(g+1) on sorted batch
    int lo = 0, hi = n;
    while (lo < hi) { int mid = (lo + hi) >> 1; if (batch[mid] < g) lo = mid + 1; else hi = mid; }
    int s = lo;
    lo = s; hi = n;
    while (lo < hi) { int mid = (lo + hi) >> 1; if (batch[mid] < g + 1) lo = mid + 1; else hi = mid; }
    int e = lo;
    int len = e - s;
    if (c == 0 && f == 0) counts[g] = len;
    int cs = s + (int)(((long long)len * c) >> 3);
    int ce = s + (int)(((long long)len * (c + 1)) >> 3);
    float acc = 0.f;
    for (int i = cs; i < ce; i++) acc += h[(size_t)i * FD + f];
    if (ce > cs) atomicAdd(&sums[g * FD + f], acc);
}

__global__ __launch_bounds__(128) void final_linear(const float* __restrict__ sums, const int* __restrict__ counts,
                                                    const float* __restrict__ Wl, const float* __restrict__ bl,
                                                    float* __restrict__ out) {
    __shared__ float p[FD];
    int g = blockIdx.x;
    int o = threadIdx.x;
    float cf = fmaxf((float)counts[g], 1.0f);
    p[o] = sums[g * FD + o] / cf;
    __syncthreads();
    float acc = bl[o];
    #pragma unroll 16
    for (int k = 0; k < FD; k++) acc = fmaf(p[k], Wl[k * FD + o], acc);
    out[g * FD + o] = acc;
}

extern "C" void kernel_launch(void* const* d_in, const int* in_sizes, int n_in,
                              void* d_out, int out_size, void* d_ws, size_t ws_size,
                              hipStream_t stream) {
    const float* x     = (const float*)d_in[0];
    const int*   ei    = (const int*)d_in[1];
    const int*   batch = (const int*)d_in[2];
    const float* W1    = (const float*)d_in[3];
    const float* b1    = (const float*)d_in[4];
    const float* W2    = (const float*)d_in[5];
    const float* b2    = (const float*)d_in[6];
    const float* Wl    = (const float*)d_in[7];
    const float* bl    = (const float*)d_in[8];

    const int E = in_sizes[1] / 2;
    const int n = in_sizes[2];
    const int G = out_size / FD;
    const int* src = ei;
    const int* dst = ei + E;

    // workspace layout (256B-aligned chunks)
    auto al = [](size_t b) { return (b + 255) & ~(size_t)255; };
    char* w = (char*)d_ws;
    size_t o_cnt     = 0;
    size_t o_cursor  = o_cnt + al((size_t)n * 4);
    size_t o_sums    = o_cursor + al((size_t)n * 4);
    size_t o_counts  = o_sums + al((size_t)G * FD * 4);
    size_t zend      = o_counts + 256;             // memset region end
    size_t o_dinv    = zend;
    size_t o_offs    = o_dinv + al((size_t)n * 4);
    size_t o_part    = o_offs + al((size_t)(n + 1) * 4);
    size_t o_csr     = o_part + 256;
    size_t o_bufA    = o_csr + al((size_t)E * 4);
    size_t o_bufB    = o_bufA + al((size_t)n * FD * 4);

    int*   cnt     = (int*)(w + o_cnt);
    int*   cursor  = (int*)(w + o_cursor);
    float* sums    = (float*)(w + o_sums);
    int*   counts  = (int*)(w + o_counts);
    float* dinv    = (float*)(w + o_dinv);
    int*   offs    = (int*)(w + o_offs);
    int*   part    = (int*)(w + o_part);
    int*   csr     = (int*)(w + o_csr);
    float* bufA    = (float*)(w + o_bufA);
    float* bufB    = (float*)(w + o_bufB);

    hipMemsetAsync(d_ws, 0, zend, stream);

    count_deg<<<(E + 255) / 256, 256, 0, stream>>>(dst, cnt, E);
    compute_dinv<<<(n + 255) / 256, 256, 0, stream>>>(cnt, dinv, n);
    int nb = (n + 1023) / 1024;
    scan1<<<nb, 1024, 0, stream>>>(cnt, offs, part, n);
    scan2<<<1, 64, 0, stream>>>(part, nb);
    scan3<<<nb, 1024, 0, stream>>>(offs, part, n);
    fill_csr<<<(E + 255) / 256, 256, 0, stream>>>(src, dst, offs, cursor, csr, E);

    gemm128<<<(n + 31) / 32, 256, 0, stream>>>(x, W1, bufA, n);
    gcn_gather<<<(n + 1) / 2, 256, 0, stream>>>(bufA, dinv, offs, cnt, csr, b1, bufB, n);
    gemm128<<<(n + 31) / 32, 256, 0, stream>>>(bufB, W2, bufA, n);
    gcn_gather<<<(n + 1) / 2, 256, 0, stream>>>(bufA, dinv, offs, cnt, csr, b2, bufB, n);

    pool_partial<<<G * 8, 128, 0, stream>>>(bufB, batch, sums, counts, n);
    final_linear<<<G, 128, 0, stream>>>(sums, counts, Wl, bl, (float*)d_out);
}

// Round 2
// 289.419 us; speedup vs baseline: 1.4866x; 1.4866x over previous
//
#include <hip/hip_runtime.h>

// GCN graph embedding: N=50000, E=600000, F=128 throughout, G=64 graphs.
// Pipeline:
//   deg count -> (dinv + exclusive scan fused) -> CSR fill
//   bufA = (x @ W1) * dinv[row]            (GEMM, dinv folded into epilogue)
//   bufB = relu(dinv[n] * (sum_nbr bufA[s] + bufA[n]) + b1)   (pure gather-add)
//   bufA = (bufB @ W2) * dinv[row]
//   bufB = relu(gather) ...
//   sums/counts = pool(bufB, batch); out = mean @ Wl + bl

#define FD 128

__global__ void count_deg(const int* __restrict__ dst, int* __restrict__ cnt, int E) {
    int e = blockIdx.x * 256 + threadIdx.x;
    if (e < E) atomicAdd(&cnt[dst[e]], 1);
}

// fused: block-local exclusive scan of cnt + dinv = rsqrt(cnt+1)
__global__ __launch_bounds__(1024) void scan1(const int* __restrict__ cnt, int* __restrict__ offs,
                                              int* __restrict__ partials, float* __restrict__ dinv, int n) {
    __shared__ int s[1024];
    int tid = threadIdx.x;
    int i = blockIdx.x * 1024 + tid;
    int v = (i < n) ? cnt[i] : 0;
    if (i < n) dinv[i] = rsqrtf((float)v + 1.0f);   // +1 self loop
    s[tid] = v;
    __syncthreads();
    for (int off = 1; off < 1024; off <<= 1) {
        int t = (tid >= off) ? s[tid - off] : 0;
        __syncthreads();
        s[tid] += t;
        __syncthreads();
    }
    if (i < n) offs[i] = s[tid] - v;            // exclusive within block
    if (tid == 1023) partials[blockIdx.x] = s[1023];
}

__global__ void scan2(int* partials, int nb) {
    if (threadIdx.x == 0 && blockIdx.x == 0) {
        int run = 0;
        for (int b = 0; b < nb; b++) { int t = partials[b]; partials[b] = run; run += t; }
    }
}

__global__ __launch_bounds__(1024) void scan3(int* __restrict__ offs, const int* __restrict__ partials, int n) {
    int i = blockIdx.x * 1024 + threadIdx.x;
    if (i < n) offs[i] += partials[blockIdx.x];
}

__global__ void fill_csr(const int* __restrict__ src, const int* __restrict__ dst,
                         const int* __restrict__ offs, int* __restrict__ cursor,
                         int* __restrict__ csr, int E) {
    int e = blockIdx.x * 256 + threadIdx.x;
    if (e < E) {
        int d = dst[e];
        int p = atomicAdd(&cursor[d], 1);
        csr[offs[d] + p] = src[e];
    }
}

// Y[rows x 128] = (X[rows x 128] @ W[128 x 128]) * scale[row]; 32 rows / 256-thread block.
__global__ __launch_bounds__(256) void gemm128(const float* __restrict__ X, const float* __restrict__ W,
                                               const float* __restrict__ scale,
                                               float* __restrict__ Y, int rows) {
    __shared__ __align__(16) float xs[32][FD];
    int tid = threadIdx.x;
    int r0 = blockIdx.x * 32;

    const float4* Xv = (const float4*)(X + (size_t)r0 * FD);
    float4* xsv = (float4*)&xs[0][0];
    #pragma unroll
    for (int j = 0; j < 4; j++) {
        int idx = tid + j * 256;
        size_t gi = (size_t)r0 * 32 + idx;
        float4 v = make_float4(0.f, 0.f, 0.f, 0.f);
        if (gi < (size_t)rows * 32) v = Xv[idx];
        xsv[idx] = v;
    }
    __syncthreads();

    int c4 = (tid & 31) * 4;
    int rg = tid >> 5;
    float acc[4][4] = {};

    #pragma unroll 8
    for (int k0 = 0; k0 < FD; k0 += 4) {
        float w[4][4];
        #pragma unroll
        for (int j = 0; j < 4; j++) {
            float4 wv = *(const float4*)&W[(size_t)(k0 + j) * FD + c4];
            w[j][0] = wv.x; w[j][1] = wv.y; w[j][2] = wv.z; w[j][3] = wv.w;
        }
        #pragma unroll
        for (int r = 0; r < 4; r++) {
            float4 xv = *(const float4*)&xs[rg * 4 + r][k0];
            #pragma unroll
            for (int c = 0; c < 4; c++) {
                acc[r][c] += xv.x * w[0][c];
                acc[r][c] += xv.y * w[1][c];
                acc[r][c] += xv.z * w[2][c];
                acc[r][c] += xv.w * w[3][c];
            }
        }
    }

    #pragma unroll
    for (int r = 0; r < 4; r++) {
        int row = r0 + rg * 4 + r;
        if (row < rows) {
            float s = scale[row];
            float4 o = make_float4(acc[r][0] * s, acc[r][1] * s, acc[r][2] * s, acc[r][3] * s);
            *(float4*)&Y[(size_t)row * FD + c4] = o;
        }
    }
}

// One node per 64-lane wave; lane covers 2 features (float2 = whole 512B row per wave).
// xw2 rows are pre-scaled by dinv[src]; out = relu(dinv[node] * (self + sum_nbr) + bias).
__global__ __launch_bounds__(256) void gcn_gather(const float2* __restrict__ xw2,
                                                  const float* __restrict__ dinv,
                                                  const int* __restrict__ offs, const int* __restrict__ cnt,
                                                  const int* __restrict__ csr, const float* __restrict__ bias,
                                                  float2* __restrict__ out, int n) {
    int wave = threadIdx.x >> 6;
    int lane = threadIdx.x & 63;
    int node = blockIdx.x * 4 + wave;
    if (node >= n) return;

    float2 acc = xw2[(size_t)node * 64 + lane];     // self loop (pre-scaled)
    int s0 = offs[node];
    int cn = cnt[node];

    for (int c = 0; c < cn; c += 64) {
        int m = min(64, cn - c);
        int idx = (lane < m) ? csr[s0 + c + lane] : 0;   // cooperative index preload
        int j = 0;
        for (; j + 4 <= m; j += 4) {
            int a0 = __shfl(idx, j + 0);
            int a1 = __shfl(idx, j + 1);
            int a2 = __shfl(idx, j + 2);
            int a3 = __shfl(idx, j + 3);
            float2 r0 = xw2[(size_t)a0 * 64 + lane];
            float2 r1 = xw2[(size_t)a1 * 64 + lane];
            float2 r2 = xw2[(size_t)a2 * 64 + lane];
            float2 r3 = xw2[(size_t)a3 * 64 + lane];
            acc.x += r0.x + r1.x + r2.x + r3.x;
            acc.y += r0.y + r1.y + r2.y + r3.y;
        }
        for (; j < m; j++) {
            int a = __shfl(idx, j);
            float2 r = xw2[(size_t)a * 64 + lane];
            acc.x += r.x;
            acc.y += r.y;
        }
    }

    float dn = dinv[node];
    float2 b = ((const float2*)bias)[lane];
    float2 o;
    o.x = fmaxf(fmaf(acc.x, dn, b.x), 0.0f);
    o.y = fmaxf(fmaf(acc.y, dn, b.y), 0.0f);
    out[(size_t)node * 64 + lane] = o;
}

__global__ __launch_bounds__(128) void pool_partial(const float* __restrict__ h, const int* __restrict__ batch,
                                                    float* __restrict__ sums, int* __restrict__ counts, int n) {
    int g = blockIdx.x >> 3;
    int c = blockIdx.x & 7;
    int f = threadIdx.x;
    int lo = 0, hi = n;
    while (lo < hi) { int mid = (lo + hi) >> 1; if (batch[mid] < g) lo = mid + 1; else hi = mid; }
    int s = lo;
    lo = s; hi = n;
    while (lo < hi) { int mid = (lo + hi) >> 1; if (batch[mid] < g + 1) lo = mid + 1; else hi = mid; }
    int e = lo;
    int len = e - s;
    if (c == 0 && f == 0) counts[g] = len;
    int cs = s + (int)(((long long)len * c) >> 3);
    int ce = s + (int)(((long long)len * (c + 1)) >> 3);
    float acc = 0.f;
    for (int i = cs; i < ce; i++) acc += h[(size_t)i * FD + f];
    if (ce > cs) atomicAdd(&sums[g * FD + f], acc);
}

__global__ __launch_bounds__(128) void final_linear(const float* __restrict__ sums, const int* __restrict__ counts,
                                                    const float* __restrict__ Wl, const float* __restrict__ bl,
                                                    float* __restrict__ out) {
    __shared__ float p[FD];
    int g = blockIdx.x;
    int o = threadIdx.x;
    float cf = fmaxf((float)counts[g], 1.0f);
    p[o] = sums[g * FD + o] / cf;
    __syncthreads();
    float acc = bl[o];
    #pragma unroll 16
    for (int k = 0; k < FD; k++) acc = fmaf(p[k], Wl[k * FD + o], acc);
    out[g * FD + o] = acc;
}

extern "C" void kernel_launch(void* const* d_in, const int* in_sizes, int n_in,
                              void* d_out, int out_size, void* d_ws, size_t ws_size,
                              hipStream_t stream) {
    const float* x     = (const float*)d_in[0];
    const int*   ei    = (const int*)d_in[1];
    const int*   batch = (const int*)d_in[2];
    const float* W1    = (const float*)d_in[3];
    const float* b1    = (const float*)d_in[4];
    const float* W2    = (const float*)d_in[5];
    const float* b2    = (const float*)d_in[6];
    const float* Wl    = (const float*)d_in[7];
    const float* bl    = (const float*)d_in[8];

    const int E = in_sizes[1] / 2;
    const int n = in_sizes[2];
    const int G = out_size / FD;
    const int* src = ei;
    const int* dst = ei + E;

    auto al = [](size_t b) { return (b + 255) & ~(size_t)255; };
    char* w = (char*)d_ws;
    size_t o_cnt     = 0;
    size_t o_cursor  = o_cnt + al((size_t)n * 4);
    size_t o_sums    = o_cursor + al((size_t)n * 4);
    size_t o_counts  = o_sums + al((size_t)G * FD * 4);
    size_t zend      = o_counts + 256;             // memset region end
    size_t o_dinv    = zend;
    size_t o_offs    = o_dinv + al((size_t)n * 4);
    size_t o_part    = o_offs + al((size_t)(n + 1) * 4);
    size_t o_csr     = o_part + 256;
    size_t o_bufA    = o_csr + al((size_t)E * 4);
    size_t o_bufB    = o_bufA + al((size_t)n * FD * 4);

    int*   cnt     = (int*)(w + o_cnt);
    int*   cursor  = (int*)(w + o_cursor);
    float* sums    = (float*)(w + o_sums);
    int*   counts  = (int*)(w + o_counts);
    float* dinv    = (float*)(w + o_dinv);
    int*   offs    = (int*)(w + o_offs);
    int*   part    = (int*)(w + o_part);
    int*   csr     = (int*)(w + o_csr);
    float* bufA    = (float*)(w + o_bufA);
    float* bufB    = (float*)(w + o_bufB);

    hipMemsetAsync(d_ws, 0, zend, stream);

    count_deg<<<(E + 255) / 256, 256, 0, stream>>>(dst, cnt, E);
    int nb = (n + 1023) / 1024;
    scan1<<<nb, 1024, 0, stream>>>(cnt, offs, part, dinv, n);
    scan2<<<1, 64, 0, stream>>>(part, nb);
    scan3<<<nb, 1024, 0, stream>>>(offs, part, n);
    fill_csr<<<(E + 255) / 256, 256, 0, stream>>>(src, dst, offs, cursor, csr, E);

    gemm128<<<(n + 31) / 32, 256, 0, stream>>>(x, W1, dinv, bufA, n);
    gcn_gather<<<(n + 3) / 4, 256, 0, stream>>>((const float2*)bufA, dinv, offs, cnt, csr, b1, (float2*)bufB, n);
    gemm128<<<(n + 31) / 32, 256, 0, stream>>>(bufB, W2, dinv, bufA, n);
    gcn_gather<<<(n + 3) / 4, 256, 0, stream>>>((const float2*)bufA, dinv, offs, cnt, csr, b2, (float2*)bufB, n);

    pool_partial<<<G * 8, 128, 0, stream>>>(bufB, batch, sums, counts, n);
    final_linear<<<G, 128, 0, stream>>>(sums, counts, Wl, bl, (float*)d_out);
}

// Round 3
// 251.870 us; speedup vs baseline: 1.7082x; 1.1491x over previous
//
#include <hip/hip_runtime.h>

// GCN graph embedding: N=50000, E=600000, F=128 throughout, G=64 graphs.
//   deg count -> (dinv + scan fused) -> CSR fill
//   pack W1,W2 into bf16 hi/lo MFMA fragment order
//   bufA = (x @ W1) * dinv[row]      (split-bf16 MFMA GEMM, dinv in epilogue)
//   bufB = relu(dinv[n] * (self + sum_nbr bufA[s]) + b1)
//   bufA = (bufB @ W2) * dinv[row];  bufB = relu(gather)
//   pool (sorted batch) -> final linear

#define FD 128

typedef __attribute__((ext_vector_type(8))) short s16x8;
typedef __attribute__((ext_vector_type(4))) float f32x4;

__device__ inline unsigned short f2bf(float f) {
    unsigned u = __float_as_uint(f);
    unsigned r = (u + 0x7FFFu + ((u >> 16) & 1u)) >> 16;
    return (unsigned short)r;
}
__device__ inline float bf2f(unsigned short h) {
    unsigned u = ((unsigned)h) << 16;
    return __uint_as_float(u);
}

__global__ void count_deg(const int* __restrict__ dst, int* __restrict__ cnt, int E) {
    int e = blockIdx.x * 256 + threadIdx.x;
    if (e < E) atomicAdd(&cnt[dst[e]], 1);
}

// fused: block-local exclusive scan of cnt + dinv = rsqrt(cnt+1)
__global__ __launch_bounds__(1024) void scan1(const int* __restrict__ cnt, int* __restrict__ offs,
                                              int* __restrict__ partials, float* __restrict__ dinv, int n) {
    __shared__ int s[1024];
    int tid = threadIdx.x;
    int i = blockIdx.x * 1024 + tid;
    int v = (i < n) ? cnt[i] : 0;
    if (i < n) dinv[i] = rsqrtf((float)v + 1.0f);   // +1 self loop
    s[tid] = v;
    __syncthreads();
    for (int off = 1; off < 1024; off <<= 1) {
        int t = (tid >= off) ? s[tid - off] : 0;
        __syncthreads();
        s[tid] += t;
        __syncthreads();
    }
    if (i < n) offs[i] = s[tid] - v;            // exclusive within block
    if (tid == 1023) partials[blockIdx.x] = s[1023];
}

// wave-parallel exclusive scan of the <=64 block partials
__global__ void scan2(int* partials, int nb) {
    int t = threadIdx.x;              // 64 threads
    int orig = (t < nb) ? partials[t] : 0;
    int v = orig;
    #pragma unroll
    for (int off = 1; off < 64; off <<= 1) {
        int u = __shfl_up(v, off);
        if (t >= off) v += u;
    }
    if (t < nb) partials[t] = v - orig;   // exclusive
}

__global__ __launch_bounds__(1024) void scan3(int* __restrict__ offs, const int* __restrict__ partials, int n) {
    int i = blockIdx.x * 1024 + threadIdx.x;
    if (i < n) offs[i] += partials[blockIdx.x];
}

__global__ void fill_csr(const int* __restrict__ src, const int* __restrict__ dst,
                         const int* __restrict__ offs, int* __restrict__ cursor,
                         int* __restrict__ csr, int E) {
    int e = blockIdx.x * 256 + threadIdx.x;
    if (e < E) {
        int d = dst[e];
        int p = atomicAdd(&cursor[d], 1);
        csr[offs[d] + p] = src[e];
    }
}

// Pack W[128x128] fp32 into bf16 hi/lo in MFMA B-fragment order:
//   slot((ks,ct,lane,j)) <- W[k = ks*32 + (lane>>4)*8 + j][col = ct*16 + (lane&15)]
// Same slot->k mapping as the A-fragment LDS read, so any HW k-permutation cancels.
__global__ __launch_bounds__(256) void pack_w(const float* __restrict__ W,
                                              unsigned short* __restrict__ Bh,
                                              unsigned short* __restrict__ Bl) {
    int t = blockIdx.x * 256 + threadIdx.x;   // 16384 slots
    int j = t & 7;
    int lane = (t >> 3) & 63;
    int ct = (t >> 9) & 7;
    int ks = t >> 12;
    int col = ct * 16 + (lane & 15);
    int k = ks * 32 + ((lane >> 4) & 3) * 8 + j;
    float w = W[(size_t)k * FD + col];
    unsigned short h = f2bf(w);
    unsigned short l = f2bf(w - bf2f(h));
    Bh[t] = h;
    Bl[t] = l;
}

// Y[rows x 128] = (X[rows x 128] @ W) * scale[row], split-bf16 MFMA.
// 64 rows / 256-thread block (4 waves x 16 rows). W via packed fragments (global/L2).
__global__ __launch_bounds__(256) void gemm_mfma(const float* __restrict__ X,
                                                 const unsigned short* __restrict__ Bh,
                                                 const unsigned short* __restrict__ Bl,
                                                 const float* __restrict__ scale,
                                                 float* __restrict__ Y, int rows) {
    __shared__ unsigned short ah[64][FD + 8];
    __shared__ unsigned short al[64][FD + 8];
    int tid = threadIdx.x;
    int r0 = blockIdx.x * 64;

    // stage + split-convert X tile: 2048 float4 chunks, 8 per thread
    #pragma unroll
    for (int jj = 0; jj < 8; jj++) {
        int idx = tid + jj * 256;
        int r = idx >> 5;              // 32 float4 per row
        int c4 = (idx & 31) * 4;
        float4 v = make_float4(0.f, 0.f, 0.f, 0.f);
        if (r0 + r < rows) v = *(const float4*)&X[(size_t)(r0 + r) * FD + c4];
        float vv[4] = {v.x, v.y, v.z, v.w};
        #pragma unroll
        for (int q = 0; q < 4; q++) {
            unsigned short h = f2bf(vv[q]);
            unsigned short l = f2bf(vv[q] - bf2f(h));
            ah[r][c4 + q] = h;
            al[r][c4 + q] = l;
        }
    }
    __syncthreads();

    int wv = tid >> 6;
    int lane = tid & 63;
    int arow = wv * 16 + (lane & 15);
    int kg = lane >> 4;                  // 0..3

    f32x4 acc[8];
    #pragma unroll
    for (int ct = 0; ct < 8; ct++) acc[ct] = (f32x4){0.f, 0.f, 0.f, 0.f};

    #pragma unroll
    for (int ks = 0; ks < 4; ks++) {
        int k0 = ks * 32 + kg * 8;
        s16x8 a_h = *(const s16x8*)&ah[arow][k0];
        s16x8 a_l = *(const s16x8*)&al[arow][k0];
        #pragma unroll
        for (int ct = 0; ct < 8; ct++) {
            size_t bidx = ((size_t)(ks * 8 + ct) * 64 + lane) * 8;
            s16x8 b_h = *(const s16x8*)&Bh[bidx];
            s16x8 b_l = *(const s16x8*)&Bl[bidx];
            acc[ct] = __builtin_amdgcn_mfma_f32_16x16x32_bf16(a_h, b_h, acc[ct], 0, 0, 0);
            acc[ct] = __builtin_amdgcn_mfma_f32_16x16x32_bf16(a_h, b_l, acc[ct], 0, 0, 0);
            acc[ct] = __builtin_amdgcn_mfma_f32_16x16x32_bf16(a_l, b_h, acc[ct], 0, 0, 0);
        }
    }

    // C/D: col = lane&15, row = (lane>>4)*4 + reg   [HW-verified mapping]
    int ccol = lane & 15;
    float sc[4];
    int rbase = r0 + wv * 16 + kg * 4;
    #pragma unroll
    for (int rg = 0; rg < 4; rg++) sc[rg] = (rbase + rg < rows) ? scale[rbase + rg] : 0.f;
    #pragma unroll
    for (int ct = 0; ct < 8; ct++) {
        #pragma unroll
        for (int rg = 0; rg < 4; rg++) {
            int row = rbase + rg;
            if (row < rows)
                Y[(size_t)row * FD + ct * 16 + ccol] = acc[ct][rg] * sc[rg];
        }
    }
}

// One node per 64-lane wave; lane covers 2 features (float2 = whole 512B row per wave).
// xw2 rows are pre-scaled by dinv[src]; out = relu(dinv[node] * (self + sum_nbr) + bias).
__global__ __launch_bounds__(256) void gcn_gather(const float2* __restrict__ xw2,
                                                  const float* __restrict__ dinv,
                                                  const int* __restrict__ offs, const int* __restrict__ cnt,
                                                  const int* __restrict__ csr, const float* __restrict__ bias,
                                                  float2* __restrict__ out, int n) {
    int wave = threadIdx.x >> 6;
    int lane = threadIdx.x & 63;
    int node = blockIdx.x * 4 + wave;
    if (node >= n) return;

    float2 acc = xw2[(size_t)node * 64 + lane];     // self loop (pre-scaled)
    int s0 = offs[node];
    int cn = cnt[node];

    for (int c = 0; c < cn; c += 64) {
        int m = min(64, cn - c);
        int idx = (lane < m) ? csr[s0 + c + lane] : 0;   // cooperative index preload
        int j = 0;
        for (; j + 4 <= m; j += 4) {
            int a0 = __shfl(idx, j + 0);
            int a1 = __shfl(idx, j + 1);
            int a2 = __shfl(idx, j + 2);
            int a3 = __shfl(idx, j + 3);
            float2 r0 = xw2[(size_t)a0 * 64 + lane];
            float2 r1 = xw2[(size_t)a1 * 64 + lane];
            float2 r2 = xw2[(size_t)a2 * 64 + lane];
            float2 r3 = xw2[(size_t)a3 * 64 + lane];
            acc.x += r0.x + r1.x + r2.x + r3.x;
            acc.y += r0.y + r1.y + r2.y + r3.y;
        }
        for (; j < m; j++) {
            int a = __shfl(idx, j);
            float2 r = xw2[(size_t)a * 64 + lane];
            acc.x += r.x;
            acc.y += r.y;
        }
    }

    float dn = dinv[node];
    float2 b = ((const float2*)bias)[lane];
    float2 o;
    o.x = fmaxf(fmaf(acc.x, dn, b.x), 0.0f);
    o.y = fmaxf(fmaf(acc.y, dn, b.y), 0.0f);
    out[(size_t)node * 64 + lane] = o;
}

__global__ __launch_bounds__(128) void pool_partial(const float* __restrict__ h, const int* __restrict__ batch,
                                                    float* __restrict__ sums, int* __restrict__ counts, int n) {
    int g = blockIdx.x >> 3;
    int c = blockIdx.x & 7;
    int f = threadIdx.x;
    int lo = 0, hi = n;
    while (lo < hi) { int mid = (lo + hi) >> 1; if (batch[mid] < g) lo = mid + 1; else hi = mid; }
    int s = lo;
    lo = s; hi = n;
    while (lo < hi) { int mid = (lo + hi) >> 1; if (batch[mid] < g + 1) lo = mid + 1; else hi = mid; }
    int e = lo;
    int len = e - s;
    if (c == 0 && f == 0) counts[g] = len;
    int cs = s + (int)(((long long)len * c) >> 3);
    int ce = s + (int)(((long long)len * (c + 1)) >> 3);
    float acc = 0.f;
    for (int i = cs; i < ce; i++) acc += h[(size_t)i * FD + f];
    if (ce > cs) atomicAdd(&sums[g * FD + f], acc);
}

__global__ __launch_bounds__(128) void final_linear(const float* __restrict__ sums, const int* __restrict__ counts,
                                                    const float* __restrict__ Wl, const float* __restrict__ bl,
                                                    float* __restrict__ out) {
    __shared__ float p[FD];
    int g = blockIdx.x;
    int o = threadIdx.x;
    float cf = fmaxf((float)counts[g], 1.0f);
    p[o] = sums[g * FD + o] / cf;
    __syncthreads();
    float acc = bl[o];
    #pragma unroll 16
    for (int k = 0; k < FD; k++) acc = fmaf(p[k], Wl[k * FD + o], acc);
    out[g * FD + o] = acc;
}

extern "C" void kernel_launch(void* const* d_in, const int* in_sizes, int n_in,
                              void* d_out, int out_size, void* d_ws, size_t ws_size,
                              hipStream_t stream) {
    const float* x     = (const float*)d_in[0];
    const int*   ei    = (const int*)d_in[1];
    const int*   batch = (const int*)d_in[2];
    const float* W1    = (const float*)d_in[3];
    const float* b1    = (const float*)d_in[4];
    const float* W2    = (const float*)d_in[5];
    const float* b2    = (const float*)d_in[6];
    const float* Wl    = (const float*)d_in[7];
    const float* bl    = (const float*)d_in[8];

    const int E = in_sizes[1] / 2;
    const int n = in_sizes[2];
    const int G = out_size / FD;
    const int* src = ei;
    const int* dst = ei + E;

    auto al = [](size_t b) { return (b + 255) & ~(size_t)255; };
    char* w = (char*)d_ws;
    size_t o_cnt     = 0;
    size_t o_cursor  = o_cnt + al((size_t)n * 4);
    size_t o_sums    = o_cursor + al((size_t)n * 4);
    size_t o_counts  = o_sums + al((size_t)G * FD * 4);
    size_t zend      = o_counts + 256;             // memset region end
    size_t o_dinv    = zend;
    size_t o_offs    = o_dinv + al((size_t)n * 4);
    size_t o_part    = o_offs + al((size_t)(n + 1) * 4);
    size_t o_csr     = o_part + 256;
    size_t o_bufA    = o_csr + al((size_t)E * 4);
    size_t o_bufB    = o_bufA + al((size_t)n * FD * 4);
    size_t o_bh1     = o_bufB + al((size_t)n * FD * 4);
    size_t o_bl1     = o_bh1 + al((size_t)FD * FD * 2);
    size_t o_bh2     = o_bl1 + al((size_t)FD * FD * 2);
    size_t o_bl2     = o_bh2 + al((size_t)FD * FD * 2);

    int*   cnt     = (int*)(w + o_cnt);
    int*   cursor  = (int*)(w + o_cursor);
    float* sums    = (float*)(w + o_sums);
    int*   counts  = (int*)(w + o_counts);
    float* dinv    = (float*)(w + o_dinv);
    int*   offs    = (int*)(w + o_offs);
    int*   part    = (int*)(w + o_part);
    int*   csr     = (int*)(w + o_csr);
    float* bufA    = (float*)(w + o_bufA);
    float* bufB    = (float*)(w + o_bufB);
    unsigned short* bh1 = (unsigned short*)(w + o_bh1);
    unsigned short* bl1 = (unsigned short*)(w + o_bl1);
    unsigned short* bh2 = (unsigned short*)(w + o_bh2);
    unsigned short* bl2 = (unsigned short*)(w + o_bl2);

    hipMemsetAsync(d_ws, 0, zend, stream);

    count_deg<<<(E + 255) / 256, 256, 0, stream>>>(dst, cnt, E);
    int nb = (n + 1023) / 1024;
    scan1<<<nb, 1024, 0, stream>>>(cnt, offs, part, dinv, n);
    scan2<<<1, 64, 0, stream>>>(part, nb);
    scan3<<<nb, 1024, 0, stream>>>(offs, part, n);
    fill_csr<<<(E + 255) / 256, 256, 0, stream>>>(src, dst, offs, cursor, csr, E);

    pack_w<<<64, 256, 0, stream>>>(W1, bh1, bl1);
    pack_w<<<64, 256, 0, stream>>>(W2, bh2, bl2);

    gemm_mfma<<<(n + 63) / 64, 256, 0, stream>>>(x, bh1, bl1, dinv, bufA, n);
    gcn_gather<<<(n + 3) / 4, 256, 0, stream>>>((const float2*)bufA, dinv, offs, cnt, csr, b1, (float2*)bufB, n);
    gemm_mfma<<<(n + 63) / 64, 256, 0, stream>>>(bufB, bh2, bl2, dinv, bufA, n);
    gcn_gather<<<(n + 3) / 4, 256, 0, stream>>>((const float2*)bufA, dinv, offs, cnt, csr, b2, (float2*)bufB, n);

    pool_partial<<<G * 8, 128, 0, stream>>>(bufB, batch, sums, counts, n);
    final_linear<<<G, 128, 0, stream>>>(sums, counts, Wl, bl, (float*)d_out);
}

// Round 4
// 251.590 us; speedup vs baseline: 1.7101x; 1.0011x over previous
//
#include <hip/hip_runtime.h>

// GCN graph embedding: N=50000, E=600000, F=128 throughout, G=64 graphs.
//   deg count -> (dinv + scan fused) -> CSR fill (scan2 folded into scan3)
//   pack W1,W2 into bf16 hi/lo MFMA fragment order (one kernel)
//   bufA = (x @ W1) * dinv[row]      (split-bf16 MFMA GEMM, M=32/wave)
//   bufB = relu(dinv[n] * (self + sum_nbr bufA[s]) + b1)   (16-lane-group gather)
//   bufA = (bufB @ W2) * dinv[row];  bufB = relu(gather)
//   pool (sorted batch) -> final linear

#define FD 128

typedef __attribute__((ext_vector_type(8))) short s16x8;
typedef __attribute__((ext_vector_type(4))) float f32x4;

__device__ inline unsigned short f2bf(float f) {
    unsigned u = __float_as_uint(f);
    unsigned r = (u + 0x7FFFu + ((u >> 16) & 1u)) >> 16;
    return (unsigned short)r;
}
__device__ inline float bf2f(unsigned short h) {
    unsigned u = ((unsigned)h) << 16;
    return __uint_as_float(u);
}

__global__ void count_deg(const int* __restrict__ dst, int* __restrict__ cnt, int E) {
    int e = blockIdx.x * 256 + threadIdx.x;
    if (e < E) atomicAdd(&cnt[dst[e]], 1);
}

// fused: block-local exclusive scan of cnt + dinv = rsqrt(cnt+1)
__global__ __launch_bounds__(1024) void scan1(const int* __restrict__ cnt, int* __restrict__ offs,
                                              int* __restrict__ partials, float* __restrict__ dinv, int n) {
    __shared__ int s[1024];
    int tid = threadIdx.x;
    int i = blockIdx.x * 1024 + tid;
    int v = (i < n) ? cnt[i] : 0;
    if (i < n) dinv[i] = rsqrtf((float)v + 1.0f);   // +1 self loop
    s[tid] = v;
    __syncthreads();
    for (int off = 1; off < 1024; off <<= 1) {
        int t = (tid >= off) ? s[tid - off] : 0;
        __syncthreads();
        s[tid] += t;
        __syncthreads();
    }
    if (i < n) offs[i] = s[tid] - v;            // exclusive within block
    if (tid == 1023) partials[blockIdx.x] = s[1023];
}

// scan3 with scan2 folded in: first wave computes sum(partials[0..blockIdx-1]) via reduce
__global__ __launch_bounds__(1024) void scan3(int* __restrict__ offs, const int* __restrict__ partials,
                                              int n, int nb) {
    __shared__ int base_s;
    int tid = threadIdx.x;
    if (tid < 64) {
        int lane = tid;
        int v = (lane < nb && lane < blockIdx.x) ? partials[lane] : 0;
        #pragma unroll
        for (int off = 32; off > 0; off >>= 1) v += __shfl_xor(v, off);
        if (lane == 0) base_s = v;
    }
    __syncthreads();
    int i = blockIdx.x * 1024 + tid;
    if (i < n) offs[i] += base_s;
}

__global__ void fill_csr(const int* __restrict__ src, const int* __restrict__ dst,
                         const int* __restrict__ offs, int* __restrict__ cursor,
                         int* __restrict__ csr, int E) {
    int e = blockIdx.x * 256 + threadIdx.x;
    if (e < E) {
        int d = dst[e];
        int p = atomicAdd(&cursor[d], 1);
        csr[offs[d] + p] = src[e];
    }
}

// Pack W1,W2 [128x128] fp32 into bf16 hi/lo in MFMA B-fragment order:
//   slot((ks,ct,lane,j)) <- W[k = ks*32 + (lane>>4)*8 + j][col = ct*16 + (lane&15)]
__global__ __launch_bounds__(256) void pack_w2(const float* __restrict__ W1, const float* __restrict__ W2,
                                               unsigned short* __restrict__ Bh1, unsigned short* __restrict__ Bl1,
                                               unsigned short* __restrict__ Bh2, unsigned short* __restrict__ Bl2) {
    int g = blockIdx.x * 256 + threadIdx.x;   // 32768 slots
    int which = g >> 14;
    int t = g & 16383;
    int j = t & 7;
    int lane = (t >> 3) & 63;
    int ct = (t >> 9) & 7;
    int ks = t >> 12;
    int col = ct * 16 + (lane & 15);
    int k = ks * 32 + ((lane >> 4) & 3) * 8 + j;
    const float* W = which ? W2 : W1;
    float w = W[(size_t)k * FD + col];
    unsigned short h = f2bf(w);
    unsigned short l = f2bf(w - bf2f(h));
    if (which) { Bh2[t] = h; Bl2[t] = l; }
    else       { Bh1[t] = h; Bl1[t] = l; }
}

// Y[rows x 128] = (X[rows x 128] @ W) * scale[row], split-bf16 MFMA.
// 128 rows / 256-thread block; each wave owns 32 rows (two 16-row fragments).
__global__ __launch_bounds__(256) void gemm_mfma(const float* __restrict__ X,
                                                 const unsigned short* __restrict__ Bh,
                                                 const unsigned short* __restrict__ Bl,
                                                 const float* __restrict__ scale,
                                                 float* __restrict__ Y, int rows) {
    __shared__ unsigned short ah[128][FD + 8];
    __shared__ unsigned short al[128][FD + 8];
    int tid = threadIdx.x;
    int r0 = blockIdx.x * 128;

    // stage + split-convert X tile: 4096 float4 chunks, 16 per thread
    #pragma unroll
    for (int jj = 0; jj < 16; jj++) {
        int idx = tid + jj * 256;
        int r = idx >> 5;              // 32 float4 per row
        int c4 = (idx & 31) * 4;
        float4 v = make_float4(0.f, 0.f, 0.f, 0.f);
        if (r0 + r < rows) v = *(const float4*)&X[(size_t)(r0 + r) * FD + c4];
        float vv[4] = {v.x, v.y, v.z, v.w};
        #pragma unroll
        for (int q = 0; q < 4; q++) {
            unsigned short h = f2bf(vv[q]);
            unsigned short l = f2bf(vv[q] - bf2f(h));
            ah[r][c4 + q] = h;
            al[r][c4 + q] = l;
        }
    }
    __syncthreads();

    int wv = tid >> 6;
    int lane = tid & 63;
    int arow0 = wv * 32 + (lane & 15);
    int arow1 = arow0 + 16;
    int kg = lane >> 4;                  // 0..3

    f32x4 acc[2][8];
    #pragma unroll
    for (int rt = 0; rt < 2; rt++)
        #pragma unroll
        for (int ct = 0; ct < 8; ct++) acc[rt][ct] = (f32x4){0.f, 0.f, 0.f, 0.f};

    #pragma unroll
    for (int ks = 0; ks < 4; ks++) {
        int k0 = ks * 32 + kg * 8;
        s16x8 a0h = *(const s16x8*)&ah[arow0][k0];
        s16x8 a0l = *(const s16x8*)&al[arow0][k0];
        s16x8 a1h = *(const s16x8*)&ah[arow1][k0];
        s16x8 a1l = *(const s16x8*)&al[arow1][k0];
        #pragma unroll
        for (int ct = 0; ct < 8; ct++) {
            int bidx = ((ks * 8 + ct) * 64 + lane) * 8;
            s16x8 b_h = *(const s16x8*)&Bh[bidx];
            s16x8 b_l = *(const s16x8*)&Bl[bidx];
            acc[0][ct] = __builtin_amdgcn_mfma_f32_16x16x32_bf16(a0h, b_h, acc[0][ct], 0, 0, 0);
            acc[0][ct] = __builtin_amdgcn_mfma_f32_16x16x32_bf16(a0h, b_l, acc[0][ct], 0, 0, 0);
            acc[0][ct] = __builtin_amdgcn_mfma_f32_16x16x32_bf16(a0l, b_h, acc[0][ct], 0, 0, 0);
            acc[1][ct] = __builtin_amdgcn_mfma_f32_16x16x32_bf16(a1h, b_h, acc[1][ct], 0, 0, 0);
            acc[1][ct] = __builtin_amdgcn_mfma_f32_16x16x32_bf16(a1h, b_l, acc[1][ct], 0, 0, 0);
            acc[1][ct] = __builtin_amdgcn_mfma_f32_16x16x32_bf16(a1l, b_h, acc[1][ct], 0, 0, 0);
        }
    }

    // C/D: col = lane&15, row = (lane>>4)*4 + reg   [HW-verified mapping]
    int ccol = lane & 15;
    #pragma unroll
    for (int rt = 0; rt < 2; rt++) {
        int rbase = r0 + wv * 32 + rt * 16 + kg * 4;
        #pragma unroll
        for (int rg = 0; rg < 4; rg++) {
            int row = rbase + rg;
            if (row < rows) {
                float s = scale[row];
                #pragma unroll
                for (int ct = 0; ct < 8; ct++)
                    Y[(size_t)row * FD + ct * 16 + ccol] = acc[rt][ct][rg] * s;
            }
        }
    }
}

// 4 nodes per wave: 16-lane groups, float4 lanes (2 x 16B per 512B row).
// xw4 rows pre-scaled by dinv[src]; out = relu(dinv[node]*(self+sum_nbr)+bias).
__global__ __launch_bounds__(256) void gcn_gather(const float4* __restrict__ xw4,
                                                  const float* __restrict__ dinv,
                                                  const int* __restrict__ offs, const int* __restrict__ cnt,
                                                  const int* __restrict__ csr, const float* __restrict__ bias,
                                                  float4* __restrict__ out, int n) {
    int lane = threadIdx.x & 63;
    int wv = threadIdx.x >> 6;
    int grp = lane >> 4;
    int sub = lane & 15;
    int node = blockIdx.x * 16 + wv * 4 + grp;
    bool valid = node < n;
    int nd = valid ? node : 0;

    int rb = nd * 32;
    float4 acc0 = xw4[rb + sub];            // self loop halves (pre-scaled)
    float4 acc1 = xw4[rb + sub + 16];
    int s0 = valid ? offs[nd] : 0;
    int cn = valid ? cnt[nd] : 0;

    for (int c = 0; c < cn; c += 16) {
        int m = min(16, cn - c);
        int idx = (sub < m) ? csr[s0 + c + sub] : 0;
        int j = 0;
        for (; j + 4 <= m; j += 4) {
            int a0 = __shfl(idx, j + 0, 16) * 32;
            int a1 = __shfl(idx, j + 1, 16) * 32;
            int a2 = __shfl(idx, j + 2, 16) * 32;
            int a3 = __shfl(idx, j + 3, 16) * 32;
            float4 p0 = xw4[a0 + sub], q0 = xw4[a0 + sub + 16];
            float4 p1 = xw4[a1 + sub], q1 = xw4[a1 + sub + 16];
            float4 p2 = xw4[a2 + sub], q2 = xw4[a2 + sub + 16];
            float4 p3 = xw4[a3 + sub], q3 = xw4[a3 + sub + 16];
            acc0.x += p0.x + p1.x + p2.x + p3.x;
            acc0.y += p0.y + p1.y + p2.y + p3.y;
            acc0.z += p0.z + p1.z + p2.z + p3.z;
            acc0.w += p0.w + p1.w + p2.w + p3.w;
            acc1.x += q0.x + q1.x + q2.x + q3.x;
            acc1.y += q0.y + q1.y + q2.y + q3.y;
            acc1.z += q0.z + q1.z + q2.z + q3.z;
            acc1.w += q0.w + q1.w + q2.w + q3.w;
        }
        for (; j < m; j++) {
            int a = __shfl(idx, j, 16) * 32;
            float4 p = xw4[a + sub], q = xw4[a + sub + 16];
            acc0.x += p.x; acc0.y += p.y; acc0.z += p.z; acc0.w += p.w;
            acc1.x += q.x; acc1.y += q.y; acc1.z += q.z; acc1.w += q.w;
        }
    }

    if (valid) {
        float dn = dinv[nd];
        const float4* bias4 = (const float4*)bias;
        float4 b0 = bias4[sub], b1 = bias4[sub + 16];
        float4 o0, o1;
        o0.x = fmaxf(fmaf(acc0.x, dn, b0.x), 0.f);
        o0.y = fmaxf(fmaf(acc0.y, dn, b0.y), 0.f);
        o0.z = fmaxf(fmaf(acc0.z, dn, b0.z), 0.f);
        o0.w = fmaxf(fmaf(acc0.w, dn, b0.w), 0.f);
        o1.x = fmaxf(fmaf(acc1.x, dn, b1.x), 0.f);
        o1.y = fmaxf(fmaf(acc1.y, dn, b1.y), 0.f);
        o1.z = fmaxf(fmaf(acc1.z, dn, b1.z), 0.f);
        o1.w = fmaxf(fmaf(acc1.w, dn, b1.w), 0.f);
        out[rb + sub] = o0;
        out[rb + sub + 16] = o1;
    }
}

__global__ __launch_bounds__(128) void pool_partial(const float* __restrict__ h, const int* __restrict__ batch,
                                                    float* __restrict__ sums, int* __restrict__ counts, int n) {
    int g = blockIdx.x >> 3;
    int c = blockIdx.x & 7;
    int f = threadIdx.x;
    int lo = 0, hi = n;
    while (lo < hi) { int mid = (lo + hi) >> 1; if (batch[mid] < g) lo = mid + 1; else hi = mid; }
    int s = lo;
    lo = s; hi = n;
    while (lo < hi) { int mid = (lo + hi) >> 1; if (batch[mid] < g + 1) lo = mid + 1; else hi = mid; }
    int e = lo;
    int len = e - s;
    if (c == 0 && f == 0) counts[g] = len;
    int cs = s + (int)(((long long)len * c) >> 3);
    int ce = s + (int)(((long long)len * (c + 1)) >> 3);
    float acc = 0.f;
    for (int i = cs; i < ce; i++) acc += h[(size_t)i * FD + f];
    if (ce > cs) atomicAdd(&sums[g * FD + f], acc);
}

__global__ __launch_bounds__(128) void final_linear(const float* __restrict__ sums, const int* __restrict__ counts,
                                                    const float* __restrict__ Wl, const float* __restrict__ bl,
                                                    float* __restrict__ out) {
    __shared__ float p[FD];
    int g = blockIdx.x;
    int o = threadIdx.x;
    float cf = fmaxf((float)counts[g], 1.0f);
    p[o] = sums[g * FD + o] / cf;
    __syncthreads();
    float acc = bl[o];
    #pragma unroll 16
    for (int k = 0; k < FD; k++) acc = fmaf(p[k], Wl[k * FD + o], acc);
    out[g * FD + o] = acc;
}

extern "C" void kernel_launch(void* const* d_in, const int* in_sizes, int n_in,
                              void* d_out, int out_size, void* d_ws, size_t ws_size,
                              hipStream_t stream) {
    const float* x     = (const float*)d_in[0];
    const int*   ei    = (const int*)d_in[1];
    const int*   batch = (const int*)d_in[2];
    const float* W1    = (const float*)d_in[3];
    const float* b1    = (const float*)d_in[4];
    const float* W2    = (const float*)d_in[5];
    const float* b2    = (const float*)d_in[6];
    const float* Wl    = (const float*)d_in[7];
    const float* bl    = (const float*)d_in[8];

    const int E = in_sizes[1] / 2;
    const int n = in_sizes[2];
    const int G = out_size / FD;
    const int* src = ei;
    const int* dst = ei + E;

    auto al = [](size_t b) { return (b + 255) & ~(size_t)255; };
    char* w = (char*)d_ws;
    size_t o_cnt     = 0;
    size_t o_cursor  = o_cnt + al((size_t)n * 4);
    size_t o_sums    = o_cursor + al((size_t)n * 4);
    size_t o_counts  = o_sums + al((size_t)G * FD * 4);
    size_t zend      = o_counts + 256;             // memset region end
    size_t o_dinv    = zend;
    size_t o_offs    = o_dinv + al((size_t)n * 4);
    size_t o_part    = o_offs + al((size_t)(n + 1) * 4);
    size_t o_csr     = o_part + 256;
    size_t o_bufA    = o_csr + al((size_t)E * 4);
    size_t o_bufB    = o_bufA + al((size_t)n * FD * 4);
    size_t o_bh1     = o_bufB + al((size_t)n * FD * 4);
    size_t o_bl1     = o_bh1 + al((size_t)FD * FD * 2);
    size_t o_bh2     = o_bl1 + al((size_t)FD * FD * 2);
    size_t o_bl2     = o_bh2 + al((size_t)FD * FD * 2);

    int*   cnt     = (int*)(w + o_cnt);
    int*   cursor  = (int*)(w + o_cursor);
    float* sums    = (float*)(w + o_sums);
    int*   counts  = (int*)(w + o_counts);
    float* dinv    = (float*)(w + o_dinv);
    int*   offs    = (int*)(w + o_offs);
    int*   part    = (int*)(w + o_part);
    int*   csr     = (int*)(w + o_csr);
    float* bufA    = (float*)(w + o_bufA);
    float* bufB    = (float*)(w + o_bufB);
    unsigned short* bh1 = (unsigned short*)(w + o_bh1);
    unsigned short* bl1 = (unsigned short*)(w + o_bl1);
    unsigned short* bh2 = (unsigned short*)(w + o_bh2);
    unsigned short* bl2 = (unsigned short*)(w + o_bl2);

    hipMemsetAsync(d_ws, 0, zend, stream);

    count_deg<<<(E + 255) / 256, 256, 0, stream>>>(dst, cnt, E);
    int nb = (n + 1023) / 1024;
    scan1<<<nb, 1024, 0, stream>>>(cnt, offs, part, dinv, n);
    scan3<<<nb, 1024, 0, stream>>>(offs, part, n, nb);
    fill_csr<<<(E + 255) / 256, 256, 0, stream>>>(src, dst, offs, cursor, csr, E);

    pack_w2<<<128, 256, 0, stream>>>(W1, W2, bh1, bl1, bh2, bl2);

    gemm_mfma<<<(n + 127) / 128, 256, 0, stream>>>(x, bh1, bl1, dinv, bufA, n);
    gcn_gather<<<(n + 15) / 16, 256, 0, stream>>>((const float4*)bufA, dinv, offs, cnt, csr, b1, (float4*)bufB, n);
    gemm_mfma<<<(n + 127) / 128, 256, 0, stream>>>(bufB, bh2, bl2, dinv, bufA, n);
    gcn_gather<<<(n + 15) / 16, 256, 0, stream>>>((const float4*)bufA, dinv, offs, cnt, csr, b2, (float4*)bufB, n);

    pool_partial<<<G * 8, 128, 0, stream>>>(bufB, batch, sums, counts, n);
    final_linear<<<G, 128, 0, stream>>>(sums, counts, Wl, bl, (float*)d_out);
}

// Round 5
// 211.732 us; speedup vs baseline: 2.0320x; 1.1882x over previous
//
#include <hip/hip_runtime.h>

// GCN graph embedding: N=50000, E=600000, F=128 throughout, G=64 graphs.
//   deg count -> (dinv + scan fused) -> CSR fill
//   pack W1,W2 into bf16 hi/lo MFMA fragment order (one kernel)
//   Ybf = bf16[(x @ W1) * dinv[row]]         (split-bf16 MFMA GEMM, bf16 output)
//   bufB = relu(dinv[n]*(self+sum_nbr Ybf[s]) + b1)  fp32   (bf16-payload gather)
//   Ybf = bf16[(bufB @ W2) * dinv[row]]
//   hbf = relu(gather)  -> bf16
//   pool (sorted batch, bf16 input) -> final linear

#define FD 128

typedef __attribute__((ext_vector_type(8))) short s16x8;
typedef __attribute__((ext_vector_type(4))) float f32x4;

__device__ inline unsigned short f2bf(float f) {
    unsigned u = __float_as_uint(f);
    unsigned r = (u + 0x7FFFu + ((u >> 16) & 1u)) >> 16;
    return (unsigned short)r;
}
__device__ inline float bf2f(unsigned short h) {
    return __uint_as_float(((unsigned)h) << 16);
}

__global__ void count_deg(const int* __restrict__ dst, int* __restrict__ cnt, int E) {
    int e = blockIdx.x * 256 + threadIdx.x;
    if (e < E) atomicAdd(&cnt[dst[e]], 1);
}

// fused: block-local exclusive scan of cnt + dinv = rsqrt(cnt+1)
__global__ __launch_bounds__(1024) void scan1(const int* __restrict__ cnt, int* __restrict__ offs,
                                              int* __restrict__ partials, float* __restrict__ dinv, int n) {
    __shared__ int s[1024];
    int tid = threadIdx.x;
    int i = blockIdx.x * 1024 + tid;
    int v = (i < n) ? cnt[i] : 0;
    if (i < n) dinv[i] = rsqrtf((float)v + 1.0f);   // +1 self loop
    s[tid] = v;
    __syncthreads();
    for (int off = 1; off < 1024; off <<= 1) {
        int t = (tid >= off) ? s[tid - off] : 0;
        __syncthreads();
        s[tid] += t;
        __syncthreads();
    }
    if (i < n) offs[i] = s[tid] - v;            // exclusive within block
    if (tid == 1023) partials[blockIdx.x] = s[1023];
}

// scan3 with scan2 folded in: first wave computes sum(partials[0..blockIdx-1]) via reduce
__global__ __launch_bounds__(1024) void scan3(int* __restrict__ offs, const int* __restrict__ partials,
                                              int n, int nb) {
    __shared__ int base_s;
    int tid = threadIdx.x;
    if (tid < 64) {
        int lane = tid;
        int v = (lane < nb && lane < blockIdx.x) ? partials[lane] : 0;
        #pragma unroll
        for (int off = 32; off > 0; off >>= 1) v += __shfl_xor(v, off);
        if (lane == 0) base_s = v;
    }
    __syncthreads();
    int i = blockIdx.x * 1024 + tid;
    if (i < n) offs[i] += base_s;
}

__global__ void fill_csr(const int* __restrict__ src, const int* __restrict__ dst,
                         const int* __restrict__ offs, int* __restrict__ cursor,
                         int* __restrict__ csr, int E) {
    int e = blockIdx.x * 256 + threadIdx.x;
    if (e < E) {
        int d = dst[e];
        int p = atomicAdd(&cursor[d], 1);
        csr[offs[d] + p] = src[e];
    }
}

// Pack W1,W2 [128x128] fp32 into bf16 hi/lo in MFMA B-fragment order:
//   slot((ks,ct,lane,j)) <- W[k = ks*32 + (lane>>4)*8 + j][col = ct*16 + (lane&15)]
__global__ __launch_bounds__(256) void pack_w2(const float* __restrict__ W1, const float* __restrict__ W2,
                                               unsigned short* __restrict__ Bh1, unsigned short* __restrict__ Bl1,
                                               unsigned short* __restrict__ Bh2, unsigned short* __restrict__ Bl2) {
    int g = blockIdx.x * 256 + threadIdx.x;   // 32768 slots
    int which = g >> 14;
    int t = g & 16383;
    int j = t & 7;
    int lane = (t >> 3) & 63;
    int ct = (t >> 9) & 7;
    int ks = t >> 12;
    int col = ct * 16 + (lane & 15);
    int k = ks * 32 + ((lane >> 4) & 3) * 8 + j;
    const float* W = which ? W2 : W1;
    float w = W[(size_t)k * FD + col];
    unsigned short h = f2bf(w);
    unsigned short l = f2bf(w - bf2f(h));
    if (which) { Bh2[t] = h; Bl2[t] = l; }
    else       { Bh1[t] = h; Bl1[t] = l; }
}

// Ybf[rows x 128] (bf16) = (X[rows x 128] @ W) * scale[row], split-bf16 MFMA.
// 128 rows / 256-thread block; each wave owns 32 rows (two 16-row fragments).
__global__ __launch_bounds__(256) void gemm_mfma(const float* __restrict__ X,
                                                 const unsigned short* __restrict__ Bh,
                                                 const unsigned short* __restrict__ Bl,
                                                 const float* __restrict__ scale,
                                                 unsigned short* __restrict__ Ybf, int rows) {
    __shared__ unsigned short ah[128][FD + 8];
    __shared__ unsigned short al[128][FD + 8];
    int tid = threadIdx.x;
    int r0 = blockIdx.x * 128;

    // stage + split-convert X tile: 4096 float4 chunks, 16 per thread
    #pragma unroll
    for (int jj = 0; jj < 16; jj++) {
        int idx = tid + jj * 256;
        int r = idx >> 5;              // 32 float4 per row
        int c4 = (idx & 31) * 4;
        float4 v = make_float4(0.f, 0.f, 0.f, 0.f);
        if (r0 + r < rows) v = *(const float4*)&X[(size_t)(r0 + r) * FD + c4];
        float vv[4] = {v.x, v.y, v.z, v.w};
        #pragma unroll
        for (int q = 0; q < 4; q++) {
            unsigned short h = f2bf(vv[q]);
            unsigned short l = f2bf(vv[q] - bf2f(h));
            ah[r][c4 + q] = h;
            al[r][c4 + q] = l;
        }
    }
    __syncthreads();

    int wv = tid >> 6;
    int lane = tid & 63;
    int arow0 = wv * 32 + (lane & 15);
    int arow1 = arow0 + 16;
    int kg = lane >> 4;                  // 0..3

    f32x4 acc[2][8];
    #pragma unroll
    for (int rt = 0; rt < 2; rt++)
        #pragma unroll
        for (int ct = 0; ct < 8; ct++) acc[rt][ct] = (f32x4){0.f, 0.f, 0.f, 0.f};

    #pragma unroll
    for (int ks = 0; ks < 4; ks++) {
        int k0 = ks * 32 + kg * 8;
        s16x8 a0h = *(const s16x8*)&ah[arow0][k0];
        s16x8 a0l = *(const s16x8*)&al[arow0][k0];
        s16x8 a1h = *(const s16x8*)&ah[arow1][k0];
        s16x8 a1l = *(const s16x8*)&al[arow1][k0];
        #pragma unroll
        for (int ct = 0; ct < 8; ct++) {
            int bidx = ((ks * 8 + ct) * 64 + lane) * 8;
            s16x8 b_h = *(const s16x8*)&Bh[bidx];
            s16x8 b_l = *(const s16x8*)&Bl[bidx];
            acc[0][ct] = __builtin_amdgcn_mfma_f32_16x16x32_bf16(a0h, b_h, acc[0][ct], 0, 0, 0);
            acc[0][ct] = __builtin_amdgcn_mfma_f32_16x16x32_bf16(a0h, b_l, acc[0][ct], 0, 0, 0);
            acc[0][ct] = __builtin_amdgcn_mfma_f32_16x16x32_bf16(a0l, b_h, acc[0][ct], 0, 0, 0);
            acc[1][ct] = __builtin_amdgcn_mfma_f32_16x16x32_bf16(a1h, b_h, acc[1][ct], 0, 0, 0);
            acc[1][ct] = __builtin_amdgcn_mfma_f32_16x16x32_bf16(a1h, b_l, acc[1][ct], 0, 0, 0);
            acc[1][ct] = __builtin_amdgcn_mfma_f32_16x16x32_bf16(a1l, b_h, acc[1][ct], 0, 0, 0);
        }
    }

    // C/D: col = lane&15, row = (lane>>4)*4 + reg   [HW-verified mapping]
    // Pack adjacent cols (lane pairs) -> u32 bf16x2 stores from even-ccol lanes.
    int ccol = lane & 15;
    #pragma unroll
    for (int rt = 0; rt < 2; rt++) {
        int rbase = r0 + wv * 32 + rt * 16 + kg * 4;
        #pragma unroll
        for (int rg = 0; rg < 4; rg++) {
            int row = rbase + rg;
            float s = (row < rows) ? scale[row] : 0.f;
            #pragma unroll
            for (int ct = 0; ct < 8; ct++) {
                float val = acc[rt][ct][rg] * s;
                float pv = __shfl_xor(val, 1);
                if (((lane & 1) == 0) && row < rows) {
                    unsigned pack = (unsigned)f2bf(val) | ((unsigned)f2bf(pv) << 16);
                    *(unsigned*)&Ybf[(size_t)row * FD + ct * 16 + ccol] = pack;
                }
            }
        }
    }
}

// 4 nodes per wave: 16-lane groups, one 16B bf16x8 load covers a lane's 8 features;
// a 16-lane group covers the whole 256B row per load. fp32 accumulate.
// OUT_BF16=0 -> fp32 out (GEMM input); OUT_BF16=1 -> bf16 out (pool input).
template <int OUT_BF16>
__global__ __launch_bounds__(256) void gcn_gather(const uint4* __restrict__ xwb,
                                                  const float* __restrict__ dinv,
                                                  const int* __restrict__ offs, const int* __restrict__ cnt,
                                                  const int* __restrict__ csr, const float* __restrict__ bias,
                                                  void* __restrict__ outp, int n) {
    int lane = threadIdx.x & 63;
    int wv = threadIdx.x >> 6;
    int grp = lane >> 4;
    int sub = lane & 15;
    int node = blockIdx.x * 16 + wv * 4 + grp;
    bool valid = node < n;
    int nd = valid ? node : 0;

    float acc[8];
    {
        uint4 v = xwb[nd * 16 + sub];    // self row (pre-scaled, bf16)
        acc[0] = __uint_as_float(v.x << 16);
        acc[1] = __uint_as_float(v.x & 0xFFFF0000u);
        acc[2] = __uint_as_float(v.y << 16);
        acc[3] = __uint_as_float(v.y & 0xFFFF0000u);
        acc[4] = __uint_as_float(v.z << 16);
        acc[5] = __uint_as_float(v.z & 0xFFFF0000u);
        acc[6] = __uint_as_float(v.w << 16);
        acc[7] = __uint_as_float(v.w & 0xFFFF0000u);
    }
    int s0 = valid ? offs[nd] : 0;
    int cn = valid ? cnt[nd] : 0;

    #define BFACC(v)                                         \
        acc[0] += __uint_as_float((v).x << 16);              \
        acc[1] += __uint_as_float((v).x & 0xFFFF0000u);      \
        acc[2] += __uint_as_float((v).y << 16);              \
        acc[3] += __uint_as_float((v).y & 0xFFFF0000u);      \
        acc[4] += __uint_as_float((v).z << 16);              \
        acc[5] += __uint_as_float((v).z & 0xFFFF0000u);      \
        acc[6] += __uint_as_float((v).w << 16);              \
        acc[7] += __uint_as_float((v).w & 0xFFFF0000u);

    for (int c = 0; c < cn; c += 16) {
        int m = min(16, cn - c);
        int idx = (sub < m) ? csr[s0 + c + sub] : 0;
        int j = 0;
        for (; j + 4 <= m; j += 4) {
            int a0 = __shfl(idx, j + 0, 16) * 16;
            int a1 = __shfl(idx, j + 1, 16) * 16;
            int a2 = __shfl(idx, j + 2, 16) * 16;
            int a3 = __shfl(idx, j + 3, 16) * 16;
            uint4 v0 = xwb[a0 + sub];
            uint4 v1 = xwb[a1 + sub];
            uint4 v2 = xwb[a2 + sub];
            uint4 v3 = xwb[a3 + sub];
            BFACC(v0); BFACC(v1); BFACC(v2); BFACC(v3);
        }
        for (; j < m; j++) {
            int a = __shfl(idx, j, 16) * 16;
            uint4 v = xwb[a + sub];
            BFACC(v);
        }
    }
    #undef BFACC

    if (valid) {
        float dn = dinv[nd];
        float o[8];
        #pragma unroll
        for (int q = 0; q < 8; q++)
            o[q] = fmaxf(fmaf(acc[q], dn, bias[sub * 8 + q]), 0.f);
        if (OUT_BF16) {
            uint4 pk;
            pk.x = (unsigned)f2bf(o[0]) | ((unsigned)f2bf(o[1]) << 16);
            pk.y = (unsigned)f2bf(o[2]) | ((unsigned)f2bf(o[3]) << 16);
            pk.z = (unsigned)f2bf(o[4]) | ((unsigned)f2bf(o[5]) << 16);
            pk.w = (unsigned)f2bf(o[6]) | ((unsigned)f2bf(o[7]) << 16);
            ((uint4*)outp)[nd * 16 + sub] = pk;
        } else {
            float4* out4 = (float4*)outp;
            out4[nd * 32 + sub * 2 + 0] = make_float4(o[0], o[1], o[2], o[3]);
            out4[nd * 32 + sub * 2 + 1] = make_float4(o[4], o[5], o[6], o[7]);
        }
    }
}

__global__ __launch_bounds__(128) void pool_partial(const unsigned short* __restrict__ h,
                                                    const int* __restrict__ batch,
                                                    float* __restrict__ sums, int* __restrict__ counts, int n) {
    int g = blockIdx.x >> 3;
    int c = blockIdx.x & 7;
    int f = threadIdx.x;
    int lo = 0, hi = n;
    while (lo < hi) { int mid = (lo + hi) >> 1; if (batch[mid] < g) lo = mid + 1; else hi = mid; }
    int s = lo;
    lo = s; hi = n;
    while (lo < hi) { int mid = (lo + hi) >> 1; if (batch[mid] < g + 1) lo = mid + 1; else hi = mid; }
    int e = lo;
    int len = e - s;
    if (c == 0 && f == 0) counts[g] = len;
    int cs = s + (int)(((long long)len * c) >> 3);
    int ce = s + (int)(((long long)len * (c + 1)) >> 3);
    float acc = 0.f;
    for (int i = cs; i < ce; i++) acc += bf2f(h[(size_t)i * FD + f]);
    if (ce > cs) atomicAdd(&sums[g * FD + f], acc);
}

__global__ __launch_bounds__(128) void final_linear(const float* __restrict__ sums, const int* __restrict__ counts,
                                                    const float* __restrict__ Wl, const float* __restrict__ bl,
                                                    float* __restrict__ out) {
    __shared__ float p[FD];
    int g = blockIdx.x;
    int o = threadIdx.x;
    float cf = fmaxf((float)counts[g], 1.0f);
    p[o] = sums[g * FD + o] / cf;
    __syncthreads();
    float acc = bl[o];
    #pragma unroll 16
    for (int k = 0; k < FD; k++) acc = fmaf(p[k], Wl[k * FD + o], acc);
    out[g * FD + o] = acc;
}

extern "C" void kernel_launch(void* const* d_in, const int* in_sizes, int n_in,
                              void* d_out, int out_size, void* d_ws, size_t ws_size,
                              hipStream_t stream) {
    const float* x     = (const float*)d_in[0];
    const int*   ei    = (const int*)d_in[1];
    const int*   batch = (const int*)d_in[2];
    const float* W1    = (const float*)d_in[3];
    const float* b1    = (const float*)d_in[4];
    const float* W2    = (const float*)d_in[5];
    const float* b2    = (const float*)d_in[6];
    const float* Wl    = (const float*)d_in[7];
    const float* bl    = (const float*)d_in[8];

    const int E = in_sizes[1] / 2;
    const int n = in_sizes[2];
    const int G = out_size / FD;
    const int* src = ei;
    const int* dst = ei + E;

    auto al = [](size_t b) { return (b + 255) & ~(size_t)255; };
    char* w = (char*)d_ws;
    size_t o_cnt     = 0;
    size_t o_cursor  = o_cnt + al((size_t)n * 4);
    size_t o_sums    = o_cursor + al((size_t)n * 4);
    size_t o_counts  = o_sums + al((size_t)G * FD * 4);
    size_t zend      = o_counts + 256;             // memset region end
    size_t o_dinv    = zend;
    size_t o_offs    = o_dinv + al((size_t)n * 4);
    size_t o_part    = o_offs + al((size_t)(n + 1) * 4);
    size_t o_csr     = o_part + 256;
    size_t o_ybf     = o_csr + al((size_t)E * 4);            // bf16 GEMM out, n*128*2
    size_t o_bufB    = o_ybf + al((size_t)n * FD * 2);       // fp32 h1
    size_t o_hbf     = o_bufB + al((size_t)n * FD * 4);      // bf16 h2
    size_t o_bh1     = o_hbf + al((size_t)n * FD * 2);
    size_t o_bl1     = o_bh1 + al((size_t)FD * FD * 2);
    size_t o_bh2     = o_bl1 + al((size_t)FD * FD * 2);
    size_t o_bl2     = o_bh2 + al((size_t)FD * FD * 2);

    int*   cnt     = (int*)(w + o_cnt);
    int*   cursor  = (int*)(w + o_cursor);
    float* sums    = (float*)(w + o_sums);
    int*   counts  = (int*)(w + o_counts);
    float* dinv    = (float*)(w + o_dinv);
    int*   offs    = (int*)(w + o_offs);
    int*   part    = (int*)(w + o_part);
    int*   csr     = (int*)(w + o_csr);
    unsigned short* ybf = (unsigned short*)(w + o_ybf);
    float* bufB    = (float*)(w + o_bufB);
    unsigned short* hbf = (unsigned short*)(w + o_hbf);
    unsigned short* bh1 = (unsigned short*)(w + o_bh1);
    unsigned short* bl1 = (unsigned short*)(w + o_bl1);
    unsigned short* bh2 = (unsigned short*)(w + o_bh2);
    unsigned short* bl2 = (unsigned short*)(w + o_bl2);

    hipMemsetAsync(d_ws, 0, zend, stream);

    count_deg<<<(E + 255) / 256, 256, 0, stream>>>(dst, cnt, E);
    int nb = (n + 1023) / 1024;
    scan1<<<nb, 1024, 0, stream>>>(cnt, offs, part, dinv, n);
    scan3<<<nb, 1024, 0, stream>>>(offs, part, n, nb);
    fill_csr<<<(E + 255) / 256, 256, 0, stream>>>(src, dst, offs, cursor, csr, E);

    pack_w2<<<128, 256, 0, stream>>>(W1, W2, bh1, bl1, bh2, bl2);

    gemm_mfma<<<(n + 127) / 128, 256, 0, stream>>>(x, bh1, bl1, dinv, ybf, n);
    gcn_gather<0><<<(n + 15) / 16, 256, 0, stream>>>((const uint4*)ybf, dinv, offs, cnt, csr, b1, bufB, n);
    gemm_mfma<<<(n + 127) / 128, 256, 0, stream>>>(bufB, bh2, bl2, dinv, ybf, n);
    gcn_gather<1><<<(n + 15) / 16, 256, 0, stream>>>((const uint4*)ybf, dinv, offs, cnt, csr, b2, hbf, n);

    pool_partial<<<G * 8, 128, 0, stream>>>(hbf, batch, sums, counts, n);
    final_linear<<<G, 128, 0, stream>>>(sums, counts, Wl, bl, (float*)d_out);
}

// Round 6
// 201.982 us; speedup vs baseline: 2.1301x; 1.0483x over previous
//
#include <hip/hip_runtime.h>

// GCN graph embedding: N=50000, E=600000, F=128 throughout, G=64 graphs.
//   zero_ws (custom, replaces slow hipMemsetAsync)
//   deg count -> (dinv + scan fused) -> CSR fill
//   pack W1,W2 into bf16 hi/lo MFMA fragment order (one kernel)
//   Ybf = bf16[(x @ W1) * dinv[row]]     (LDS-free split-bf16 MFMA GEMM)
//   bufB = relu(dinv[n]*(self+sum_nbr Ybf[s]) + b1)  fp32  (bf16-payload gather)
//   Ybf = bf16[(bufB @ W2) * dinv[row]]
//   hbf = relu(gather) -> bf16
//   pool (sorted batch, bf16 input) -> final linear

#define FD 128

typedef __attribute__((ext_vector_type(8))) short s16x8;
typedef __attribute__((ext_vector_type(4))) float f32x4;

__device__ inline unsigned short f2bf(float f) {
    unsigned u = __float_as_uint(f);
    unsigned r = (u + 0x7FFFu + ((u >> 16) & 1u)) >> 16;
    return (unsigned short)r;
}
__device__ inline float bf2f(unsigned short h) {
    return __uint_as_float(((unsigned)h) << 16);
}

__global__ void zero_ws(uint4* __restrict__ p, int n16) {
    int i = blockIdx.x * 256 + threadIdx.x;
    if (i < n16) p[i] = make_uint4(0u, 0u, 0u, 0u);
}

__global__ void count_deg(const int* __restrict__ dst, int* __restrict__ cnt, int E) {
    int e = blockIdx.x * 256 + threadIdx.x;
    if (e < E) atomicAdd(&cnt[dst[e]], 1);
}

// fused: block-local exclusive scan of cnt + dinv = rsqrt(cnt+1)
__global__ __launch_bounds__(1024) void scan1(const int* __restrict__ cnt, int* __restrict__ offs,
                                              int* __restrict__ partials, float* __restrict__ dinv, int n) {
    __shared__ int s[1024];
    int tid = threadIdx.x;
    int i = blockIdx.x * 1024 + tid;
    int v = (i < n) ? cnt[i] : 0;
    if (i < n) dinv[i] = rsqrtf((float)v + 1.0f);   // +1 self loop
    s[tid] = v;
    __syncthreads();
    for (int off = 1; off < 1024; off <<= 1) {
        int t = (tid >= off) ? s[tid - off] : 0;
        __syncthreads();
        s[tid] += t;
        __syncthreads();
    }
    if (i < n) offs[i] = s[tid] - v;            // exclusive within block
    if (tid == 1023) partials[blockIdx.x] = s[1023];
}

// scan3 with scan2 folded in: first wave computes sum(partials[0..blockIdx-1]) via reduce
__global__ __launch_bounds__(1024) void scan3(int* __restrict__ offs, const int* __restrict__ partials,
                                              int n, int nb) {
    __shared__ int base_s;
    int tid = threadIdx.x;
    if (tid < 64) {
        int lane = tid;
        int v = (lane < nb && lane < blockIdx.x) ? partials[lane] : 0;
        #pragma unroll
        for (int off = 32; off > 0; off >>= 1) v += __shfl_xor(v, off);
        if (lane == 0) base_s = v;
    }
    __syncthreads();
    int i = blockIdx.x * 1024 + tid;
    if (i < n) offs[i] += base_s;
}

__global__ void fill_csr(const int* __restrict__ src, const int* __restrict__ dst,
                         const int* __restrict__ offs, int* __restrict__ cursor,
                         int* __restrict__ csr, int E) {
    int e = blockIdx.x * 256 + threadIdx.x;
    if (e < E) {
        int d = dst[e];
        int p = atomicAdd(&cursor[d], 1);
        csr[offs[d] + p] = src[e];
    }
}

// Pack W1,W2 [128x128] fp32 into bf16 hi/lo in MFMA B-fragment order:
//   slot((ks,ct,lane,j)) <- W[k = ks*32 + (lane>>4)*8 + j][col = ct*16 + (lane&15)]
__global__ __launch_bounds__(256) void pack_w2(const float* __restrict__ W1, const float* __restrict__ W2,
                                               unsigned short* __restrict__ Bh1, unsigned short* __restrict__ Bl1,
                                               unsigned short* __restrict__ Bh2, unsigned short* __restrict__ Bl2) {
    int g = blockIdx.x * 256 + threadIdx.x;   // 32768 slots
    int which = g >> 14;
    int t = g & 16383;
    int j = t & 7;
    int lane = (t >> 3) & 63;
    int ct = (t >> 9) & 7;
    int ks = t >> 12;
    int col = ct * 16 + (lane & 15);
    int k = ks * 32 + ((lane >> 4) & 3) * 8 + j;
    const float* W = which ? W2 : W1;
    float w = W[(size_t)k * FD + col];
    unsigned short h = f2bf(w);
    unsigned short l = f2bf(w - bf2f(h));
    if (which) { Bh2[t] = h; Bl2[t] = l; }
    else       { Bh1[t] = h; Bl1[t] = l; }
}

// Ybf[rows x 128] (bf16) = (X[rows x 128] @ W) * scale[row], split-bf16 MFMA.
// LDS-free: 64 rows/block, 4 waves x one 16-row M-tile; A-fragments loaded
// directly from global (each lane reads 8 contiguous floats of its own row).
__global__ __launch_bounds__(256) void gemm_mfma(const float* __restrict__ X,
                                                 const unsigned short* __restrict__ Bh,
                                                 const unsigned short* __restrict__ Bl,
                                                 const float* __restrict__ scale,
                                                 unsigned short* __restrict__ Ybf, int rows) {
    int tid = threadIdx.x;
    int wv = tid >> 6;
    int lane = tid & 63;
    int r0 = blockIdx.x * 64;
    int arow = r0 + wv * 16 + (lane & 15);
    int kg = lane >> 4;                  // 0..3
    bool rv = arow < rows;
    const float* xrow = X + (size_t)(rv ? arow : 0) * FD;

    f32x4 acc[8];
    #pragma unroll
    for (int ct = 0; ct < 8; ct++) acc[ct] = (f32x4){0.f, 0.f, 0.f, 0.f};

    #pragma unroll
    for (int ks = 0; ks < 4; ks++) {
        int k0 = ks * 32 + kg * 8;
        float4 xa = make_float4(0.f, 0.f, 0.f, 0.f), xb = xa;
        if (rv) {
            xa = *(const float4*)&xrow[k0];
            xb = *(const float4*)&xrow[k0 + 4];
        }
        float xv[8] = {xa.x, xa.y, xa.z, xa.w, xb.x, xb.y, xb.z, xb.w};
        s16x8 a_h, a_l;
        #pragma unroll
        for (int q = 0; q < 8; q++) {
            unsigned short h = f2bf(xv[q]);
            a_h[q] = (short)h;
            a_l[q] = (short)f2bf(xv[q] - bf2f(h));
        }
        #pragma unroll
        for (int ct = 0; ct < 8; ct++) {
            int bidx = ((ks * 8 + ct) * 64 + lane) * 8;
            s16x8 b_h = *(const s16x8*)&Bh[bidx];
            s16x8 b_l = *(const s16x8*)&Bl[bidx];
            acc[ct] = __builtin_amdgcn_mfma_f32_16x16x32_bf16(a_h, b_h, acc[ct], 0, 0, 0);
            acc[ct] = __builtin_amdgcn_mfma_f32_16x16x32_bf16(a_h, b_l, acc[ct], 0, 0, 0);
            acc[ct] = __builtin_amdgcn_mfma_f32_16x16x32_bf16(a_l, b_h, acc[ct], 0, 0, 0);
        }
    }

    // C/D: col = lane&15, row = (lane>>4)*4 + reg   [HW-verified mapping]
    // Pack adjacent cols (lane pairs) -> u32 bf16x2 stores from even-ccol lanes.
    int ccol = lane & 15;
    int rbase = r0 + wv * 16 + kg * 4;
    #pragma unroll
    for (int rg = 0; rg < 4; rg++) {
        int row = rbase + rg;
        float s = (row < rows) ? scale[row] : 0.f;
        #pragma unroll
        for (int ct = 0; ct < 8; ct++) {
            float val = acc[ct][rg] * s;
            float pv = __shfl_xor(val, 1);
            if (((lane & 1) == 0) && row < rows) {
                unsigned pack = (unsigned)f2bf(val) | ((unsigned)f2bf(pv) << 16);
                *(unsigned*)&Ybf[(size_t)row * FD + ct * 16 + ccol] = pack;
            }
        }
    }
}

// 4 nodes per wave: 16-lane groups, one 16B bf16x8 load covers a lane's 8 features;
// a 16-lane group covers the whole 256B row per load. fp32 accumulate.
// OUT_BF16=0 -> fp32 out (GEMM input); OUT_BF16=1 -> bf16 out (pool input).
template <int OUT_BF16>
__global__ __launch_bounds__(256) void gcn_gather(const uint4* __restrict__ xwb,
                                                  const float* __restrict__ dinv,
                                                  const int* __restrict__ offs, const int* __restrict__ cnt,
                                                  const int* __restrict__ csr, const float* __restrict__ bias,
                                                  void* __restrict__ outp, int n) {
    int lane = threadIdx.x & 63;
    int wv = threadIdx.x >> 6;
    int grp = lane >> 4;
    int sub = lane & 15;
    int node = blockIdx.x * 16 + wv * 4 + grp;
    bool valid = node < n;
    int nd = valid ? node : 0;

    float acc[8];
    {
        uint4 v = xwb[nd * 16 + sub];    // self row (pre-scaled, bf16)
        acc[0] = __uint_as_float(v.x << 16);
        acc[1] = __uint_as_float(v.x & 0xFFFF0000u);
        acc[2] = __uint_as_float(v.y << 16);
        acc[3] = __uint_as_float(v.y & 0xFFFF0000u);
        acc[4] = __uint_as_float(v.z << 16);
        acc[5] = __uint_as_float(v.z & 0xFFFF0000u);
        acc[6] = __uint_as_float(v.w << 16);
        acc[7] = __uint_as_float(v.w & 0xFFFF0000u);
    }
    int s0 = valid ? offs[nd] : 0;
    int cn = valid ? cnt[nd] : 0;

    #define BFACC(v)                                         \
        acc[0] += __uint_as_float((v).x << 16);              \
        acc[1] += __uint_as_float((v).x & 0xFFFF0000u);      \
        acc[2] += __uint_as_float((v).y << 16);              \
        acc[3] += __uint_as_float((v).y & 0xFFFF0000u);      \
        acc[4] += __uint_as_float((v).z << 16);              \
        acc[5] += __uint_as_float((v).z & 0xFFFF0000u);      \
        acc[6] += __uint_as_float((v).w << 16);              \
        acc[7] += __uint_as_float((v).w & 0xFFFF0000u);

    for (int c = 0; c < cn; c += 16) {
        int m = min(16, cn - c);
        int idx = (sub < m) ? csr[s0 + c + sub] : 0;
        int j = 0;
        for (; j + 4 <= m; j += 4) {
            int a0 = __shfl(idx, j + 0, 16) * 16;
            int a1 = __shfl(idx, j + 1, 16) * 16;
            int a2 = __shfl(idx, j + 2, 16) * 16;
            int a3 = __shfl(idx, j + 3, 16) * 16;
            uint4 v0 = xwb[a0 + sub];
            uint4 v1 = xwb[a1 + sub];
            uint4 v2 = xwb[a2 + sub];
            uint4 v3 = xwb[a3 + sub];
            BFACC(v0); BFACC(v1); BFACC(v2); BFACC(v3);
        }
        for (; j < m; j++) {
            int a = __shfl(idx, j, 16) * 16;
            uint4 v = xwb[a + sub];
            BFACC(v);
        }
    }
    #undef BFACC

    if (valid) {
        float dn = dinv[nd];
        float o[8];
        #pragma unroll
        for (int q = 0; q < 8; q++)
            o[q] = fmaxf(fmaf(acc[q], dn, bias[sub * 8 + q]), 0.f);
        if (OUT_BF16) {
            uint4 pk;
            pk.x = (unsigned)f2bf(o[0]) | ((unsigned)f2bf(o[1]) << 16);
            pk.y = (unsigned)f2bf(o[2]) | ((unsigned)f2bf(o[3]) << 16);
            pk.z = (unsigned)f2bf(o[4]) | ((unsigned)f2bf(o[5]) << 16);
            pk.w = (unsigned)f2bf(o[6]) | ((unsigned)f2bf(o[7]) << 16);
            ((uint4*)outp)[nd * 16 + sub] = pk;
        } else {
            float4* out4 = (float4*)outp;
            out4[nd * 32 + sub * 2 + 0] = make_float4(o[0], o[1], o[2], o[3]);
            out4[nd * 32 + sub * 2 + 1] = make_float4(o[4], o[5], o[6], o[7]);
        }
    }
}

__global__ __launch_bounds__(128) void pool_partial(const unsigned short* __restrict__ h,
                                                    const int* __restrict__ batch,
                                                    float* __restrict__ sums, int* __restrict__ counts, int n) {
    int g = blockIdx.x >> 3;
    int c = blockIdx.x & 7;
    int f = threadIdx.x;
    int lo = 0, hi = n;
    while (lo < hi) { int mid = (lo + hi) >> 1; if (batch[mid] < g) lo = mid + 1; else hi = mid; }
    int s = lo;
    lo = s; hi = n;
    while (lo < hi) { int mid = (lo + hi) >> 1; if (batch[mid] < g + 1) lo = mid + 1; else hi = mid; }
    int e = lo;
    int len = e - s;
    if (c == 0 && f == 0) counts[g] = len;
    int cs = s + (int)(((long long)len * c) >> 3);
    int ce = s + (int)(((long long)len * (c + 1)) >> 3);
    float acc = 0.f;
    for (int i = cs; i < ce; i++) acc += bf2f(h[(size_t)i * FD + f]);
    if (ce > cs) atomicAdd(&sums[g * FD + f], acc);
}

__global__ __launch_bounds__(128) void final_linear(const float* __restrict__ sums, const int* __restrict__ counts,
                                                    const float* __restrict__ Wl, const float* __restrict__ bl,
                                                    float* __restrict__ out) {
    __shared__ float p[FD];
    int g = blockIdx.x;
    int o = threadIdx.x;
    float cf = fmaxf((float)counts[g], 1.0f);
    p[o] = sums[g * FD + o] / cf;
    __syncthreads();
    float acc = bl[o];
    #pragma unroll 16
    for (int k = 0; k < FD; k++) acc = fmaf(p[k], Wl[k * FD + o], acc);
    out[g * FD + o] = acc;
}

extern "C" void kernel_launch(void* const* d_in, const int* in_sizes, int n_in,
                              void* d_out, int out_size, void* d_ws, size_t ws_size,
                              hipStream_t stream) {
    const float* x     = (const float*)d_in[0];
    const int*   ei    = (const int*)d_in[1];
    const int*   batch = (const int*)d_in[2];
    const float* W1    = (const float*)d_in[3];
    const float* b1    = (const float*)d_in[4];
    const float* W2    = (const float*)d_in[5];
    const float* b2    = (const float*)d_in[6];
    const float* Wl    = (const float*)d_in[7];
    const float* bl    = (const float*)d_in[8];

    const int E = in_sizes[1] / 2;
    const int n = in_sizes[2];
    const int G = out_size / FD;
    const int* src = ei;
    const int* dst = ei + E;

    auto al = [](size_t b) { return (b + 255) & ~(size_t)255; };
    char* w = (char*)d_ws;
    size_t o_cnt     = 0;
    size_t o_cursor  = o_cnt + al((size_t)n * 4);
    size_t o_sums    = o_cursor + al((size_t)n * 4);
    size_t o_counts  = o_sums + al((size_t)G * FD * 4);
    size_t zend      = o_counts + 256;             // zeroed region end (256-aligned)
    size_t o_dinv    = zend;
    size_t o_offs    = o_dinv + al((size_t)n * 4);
    size_t o_part    = o_offs + al((size_t)(n + 1) * 4);
    size_t o_csr     = o_part + 256;
    size_t o_ybf     = o_csr + al((size_t)E * 4);            // bf16 GEMM out, n*128*2
    size_t o_bufB    = o_ybf + al((size_t)n * FD * 2);       // fp32 h1
    size_t o_hbf     = o_bufB + al((size_t)n * FD * 4);      // bf16 h2
    size_t o_bh1     = o_hbf + al((size_t)n * FD * 2);
    size_t o_bl1     = o_bh1 + al((size_t)FD * FD * 2);
    size_t o_bh2     = o_bl1 + al((size_t)FD * FD * 2);
    size_t o_bl2     = o_bh2 + al((size_t)FD * FD * 2);

    int*   cnt     = (int*)(w + o_cnt);
    int*   cursor  = (int*)(w + o_cursor);
    float* sums    = (float*)(w + o_sums);
    int*   counts  = (int*)(w + o_counts);
    float* dinv    = (float*)(w + o_dinv);
    int*   offs    = (int*)(w + o_offs);
    int*   part    = (int*)(w + o_part);
    int*   csr     = (int*)(w + o_csr);
    unsigned short* ybf = (unsigned short*)(w + o_ybf);
    float* bufB    = (float*)(w + o_bufB);
    unsigned short* hbf = (unsigned short*)(w + o_hbf);
    unsigned short* bh1 = (unsigned short*)(w + o_bh1);
    unsigned short* bl1 = (unsigned short*)(w + o_bl1);
    unsigned short* bh2 = (unsigned short*)(w + o_bh2);
    unsigned short* bl2 = (unsigned short*)(w + o_bl2);

    int n16 = (int)(zend / 16);
    zero_ws<<<(n16 + 255) / 256, 256, 0, stream>>>((uint4*)d_ws, n16);

    count_deg<<<(E + 255) / 256, 256, 0, stream>>>(dst, cnt, E);
    int nb = (n + 1023) / 1024;
    scan1<<<nb, 1024, 0, stream>>>(cnt, offs, part, dinv, n);
    scan3<<<nb, 1024, 0, stream>>>(offs, part, n, nb);
    fill_csr<<<(E + 255) / 256, 256, 0, stream>>>(src, dst, offs, cursor, csr, E);

    pack_w2<<<128, 256, 0, stream>>>(W1, W2, bh1, bl1, bh2, bl2);

    gemm_mfma<<<(n + 63) / 64, 256, 0, stream>>>(x, bh1, bl1, dinv, ybf, n);
    gcn_gather<0><<<(n + 15) / 16, 256, 0, stream>>>((const uint4*)ybf, dinv, offs, cnt, csr, b1, bufB, n);
    gemm_mfma<<<(n + 63) / 64, 256, 0, stream>>>(bufB, bh2, bl2, dinv, ybf, n);
    gcn_gather<1><<<(n + 15) / 16, 256, 0, stream>>>((const uint4*)ybf, dinv, offs, cnt, csr, b2, hbf, n);

    pool_partial<<<G * 8, 128, 0, stream>>>(hbf, batch, sums, counts, n);
    final_linear<<<G, 128, 0, stream>>>(sums, counts, Wl, bl, (float*)d_out);
}